// Round 3
// baseline (2454.416 us; speedup 1.0000x reference)
//
#include <hip/hip_runtime.h>

// ---------------------------------------------------------------------------
// 6-layer Transformer encoder, MI355X gfx950.
// fp16 MFMA (16x16x32_f16) for all GEMMs + flash attention, fp32 residual/LN
// chain. R3 fix: attn K-tile staging indexing was the 128x32 GEMM pattern
// applied to a 64x64 tile -> half of Ks uninitialized + OOB writes racing
// into Vt (NaN with fp16). Now row=c>>3, col=(c&7)*8.
// ---------------------------------------------------------------------------

typedef _Float16 f16;
typedef _Float16 half8 __attribute__((ext_vector_type(8)));
typedef float f32x4 __attribute__((ext_vector_type(4)));

constexpr int Bn = 8, Sn = 1024, Dn = 768, Hn = 12, HDn = 64, DFn = 3072, Ln = 6;
constexpr int BS = Bn * Sn;  // 8192 rows

// ---------------------------------------------------------------------------
// Weight prep: pack [Wq;Wk;Wv] per layer into (2304 x 768) fp16 + packed bias
// ---------------------------------------------------------------------------
__global__ __launch_bounds__(256) void pack_qkv(
    const float* __restrict__ Wq, const float* __restrict__ Wk, const float* __restrict__ Wv,
    const float* __restrict__ bq, const float* __restrict__ bk, const float* __restrict__ bv,
    f16* __restrict__ Wo, float* __restrict__ bo) {
  const long per = (long)Dn * Dn;  // 589824
  long i = (long)blockIdx.x * 256 + threadIdx.x;
  const long totalW = (long)Ln * 3 * per;
  if (i < totalW) {
    int l = (int)(i / (3 * per));
    long rem = i - (long)l * 3 * per;
    int which = (int)(rem / per);
    long e = rem - (long)which * per;
    const float* s = (which == 0) ? Wq : ((which == 1) ? Wk : Wv);
    Wo[i] = (f16)(s[(long)l * per + e]);
  }
  if (i < (long)Ln * 3 * Dn) {  // 13824 bias elems
    int l = (int)(i / (3 * Dn));
    int rem = (int)(i % (3 * Dn));
    int which = rem / Dn, c = rem % Dn;
    const float* s = (which == 0) ? bq : ((which == 1) ? bk : bv);
    bo[i] = s[l * Dn + c];
  }
}

__global__ __launch_bounds__(256) void f32_to_f16_k(
    const float* __restrict__ src, f16* __restrict__ dst, long n) {
  long i = ((long)blockIdx.x * 256 + threadIdx.x) * 4;
  if (i < n) {
    float4 v = *(const float4*)&src[i];
    dst[i + 0] = (f16)v.x;
    dst[i + 1] = (f16)v.y;
    dst[i + 2] = (f16)v.z;
    dst[i + 3] = (f16)v.w;
  }
}

// ---------------------------------------------------------------------------
// Embedding gather + positional encoding -> fp32 X and fp16 Xh
// ---------------------------------------------------------------------------
__global__ __launch_bounds__(256) void embed_k(
    const int* __restrict__ ids, const float* __restrict__ emb, const float* __restrict__ pe,
    float* __restrict__ Xf, f16* __restrict__ Xh) {
  const int row = blockIdx.x;           // 0..8191
  const int s = row & (Sn - 1);
  const int id = ids[row];
  const size_t eb = (size_t)id * Dn, pb = (size_t)s * Dn, ob = (size_t)row * Dn;
  for (int c = threadIdx.x; c < Dn; c += 256) {
    float v = emb[eb + c] + pe[pb + c];
    Xf[ob + c] = v;
    Xh[ob + c] = (f16)v;
  }
}

// ---------------------------------------------------------------------------
// bt-GEMM: C(M,N) = A(MxK) @ B(NxK)^T + bias, 128x128x32 tile, 4 waves.
// MODE 1: relu + fp16 out (stride N).  MODE 2: fp32 out (stride N).
// MODE 3: fp16 out split into 3 buffers of 768 cols each (QKV).
// ---------------------------------------------------------------------------
template <int MODE>
__global__ __launch_bounds__(256) void gemm_bt(
    const f16* __restrict__ A, const f16* __restrict__ Bw, const float* __restrict__ bias,
    float* __restrict__ outF, f16* __restrict__ o0, f16* __restrict__ o1, f16* __restrict__ o2,
    int M, int N, int K) {
  const int m0 = blockIdx.x * 128;
  const int n0 = blockIdx.y * 128;
  const int tid = threadIdx.x;
  const int lane = tid & 63, wave = tid >> 6;
  const int wm = wave & 1, wn = wave >> 1;
  const int l15 = lane & 15, l4 = lane >> 4;

  __shared__ __align__(16) f16 As[128 * 40];  // +8 pad: 2-way bank conflicts only
  __shared__ __align__(16) f16 Bs[128 * 40];

  const f32x4 z4 = {0.f, 0.f, 0.f, 0.f};
  f32x4 acc[4][4];
#pragma unroll
  for (int i = 0; i < 4; i++)
#pragma unroll
    for (int j = 0; j < 4; j++) acc[i][j] = z4;

  const int kr = 8 * l4;
  for (int k0 = 0; k0 < K; k0 += 32) {
#pragma unroll
    for (int cc = 0; cc < 2; cc++) {
      const int c = tid + cc * 256;        // 512 chunks of 16B per 128x32 tile
      const int row = c >> 2, col = (c & 3) * 8;
      *(int4*)&As[row * 40 + col] = *(const int4*)&A[(size_t)(m0 + row) * K + k0 + col];
      *(int4*)&Bs[row * 40 + col] = *(const int4*)&Bw[(size_t)(n0 + row) * K + k0 + col];
    }
    __syncthreads();
    half8 af[4], bfr[4];
#pragma unroll
    for (int i = 0; i < 4; i++) af[i] = *(const half8*)&As[(wm * 64 + i * 16 + l15) * 40 + kr];
#pragma unroll
    for (int j = 0; j < 4; j++) bfr[j] = *(const half8*)&Bs[(wn * 64 + j * 16 + l15) * 40 + kr];
#pragma unroll
    for (int i = 0; i < 4; i++)
#pragma unroll
      for (int j = 0; j < 4; j++)
        acc[i][j] = __builtin_amdgcn_mfma_f32_16x16x32_f16(af[i], bfr[j], acc[i][j], 0, 0, 0);
    __syncthreads();
  }

  const int colb = n0 + wn * 64;
  const int rowb = m0 + wm * 64;
#pragma unroll
  for (int j = 0; j < 4; j++) {
    const int col = colb + j * 16 + l15;
    const float bb = bias[col];
#pragma unroll
    for (int i = 0; i < 4; i++) {
      const int rb = rowb + i * 16 + l4 * 4;
#pragma unroll
      for (int r = 0; r < 4; r++) {
        float v = acc[i][j][r] + bb;
        const int row = rb + r;
        if (MODE == 1) v = fmaxf(v, 0.f);
        if (MODE == 2) {
          outF[(size_t)row * N + col] = v;
        } else if (MODE == 3) {
          const int sel = col / 768;          // block-uniform (768 % 128 == 0)
          const int cl = col - sel * 768;
          f16* op = (sel == 0) ? o0 : ((sel == 1) ? o1 : o2);
          op[(size_t)row * 768 + cl] = (f16)v;
        } else {
          o0[(size_t)row * N + col] = (f16)v;
        }
      }
    }
  }
}

// ---------------------------------------------------------------------------
// Flash attention: one block = (b,h) x 64 q-rows; 4 waves x 16 rows each.
// K/V tiles of 64 staged in LDS (V transposed, +8 pad). Online softmax.
// Output written in merged (B,S,D) layout (the o.transpose(0,2,1,3) merge).
// ---------------------------------------------------------------------------
__global__ __launch_bounds__(256) void attn_k(
    const f16* __restrict__ Qg, const f16* __restrict__ Kg, const f16* __restrict__ Vg,
    float* __restrict__ O) {
  const int bh = blockIdx.x;            // 0..95
  const int q0 = blockIdx.y * 64;
  const int b = bh / Hn, h = bh - b * Hn;
  const size_t base = (size_t)b * (Sn * Dn) + (size_t)h * (Sn * HDn);
  const f16* Qh = Qg + base;
  const f16* Kh = Kg + base;
  const f16* Vh = Vg + base;

  const int tid = threadIdx.x, lane = tid & 63, wave = tid >> 6;
  const int l15 = lane & 15, l4 = lane >> 4;

  __shared__ __align__(16) f16 Ks[64 * 72];        // (kpos, hd), padded
  __shared__ __align__(16) f16 Vt[64 * 72];        // (hd, kpos), padded
  __shared__ __align__(16) f16 Ps[4 * 16 * 72];    // per-wave P tile (q, kpos)

  const half8 aq0 = *(const half8*)&Qh[(size_t)(q0 + wave * 16 + l15) * HDn + 8 * l4];
  const half8 aq1 = *(const half8*)&Qh[(size_t)(q0 + wave * 16 + l15) * HDn + 32 + 8 * l4];

  const f32x4 z4 = {0.f, 0.f, 0.f, 0.f};
  f32x4 Oacc[4];
#pragma unroll
  for (int nt = 0; nt < 4; nt++) Oacc[nt] = z4;
  float mrow[4], lrow[4];
#pragma unroll
  for (int r = 0; r < 4; r++) { mrow[r] = -1e30f; lrow[r] = 0.f; }

  for (int kt = 0; kt < Sn / 64; ++kt) {
    // stage K tile: 64 rows x 64 cols = 512 chunks of 8 f16 (16B each)
#pragma unroll
    for (int cc = 0; cc < 2; cc++) {
      const int c = tid + cc * 256;
      const int row = c >> 3, col = (c & 7) * 8;   // 8 chunks per 64-elem row
      *(int4*)&Ks[row * 72 + col] = *(const int4*)&Kh[(size_t)(kt * 64 + row) * HDn + col];
    }
    // stage V transposed (scalar; reads coalesced)
#pragma unroll
    for (int ee = 0; ee < 16; ee++) {
      const int e = tid + ee * 256;
      const int kp = e >> 6, hd = e & 63;
      Vt[hd * 72 + kp] = Vh[(size_t)(kt * 64 + kp) * HDn + hd];
    }
    __syncthreads();

    // scores: S(16x64) = Q(16x64) @ K_tile^T, scaled by 1/sqrt(64)
    f32x4 sc[4];
#pragma unroll
    for (int nt = 0; nt < 4; nt++) {
      f32x4 z = z4;
      half8 bk0 = *(const half8*)&Ks[(nt * 16 + l15) * 72 + 8 * l4];
      half8 bk1 = *(const half8*)&Ks[(nt * 16 + l15) * 72 + 32 + 8 * l4];
      z = __builtin_amdgcn_mfma_f32_16x16x32_f16(aq0, bk0, z, 0, 0, 0);
      z = __builtin_amdgcn_mfma_f32_16x16x32_f16(aq1, bk1, z, 0, 0, 0);
      sc[nt] = z * 0.125f;
    }

    // online softmax: rows r -> C-layout row = 4*l4 + r
    float mnew[4], alpha[4];
#pragma unroll
    for (int r = 0; r < 4; r++) {
      float mx = fmaxf(fmaxf(sc[0][r], sc[1][r]), fmaxf(sc[2][r], sc[3][r]));
#pragma unroll
      for (int off = 1; off < 16; off <<= 1) mx = fmaxf(mx, __shfl_xor(mx, off));
      mnew[r] = fmaxf(mrow[r], mx);
      alpha[r] = __expf(mrow[r] - mnew[r]);
    }
    float rsum[4] = {0.f, 0.f, 0.f, 0.f};
#pragma unroll
    for (int nt = 0; nt < 4; nt++) {
#pragma unroll
      for (int r = 0; r < 4; r++) {
        float p = __expf(sc[nt][r] - mnew[r]);
        rsum[r] += p;
        Ps[wave * 1152 + (l4 * 4 + r) * 72 + nt * 16 + l15] = (f16)p;
      }
    }
#pragma unroll
    for (int r = 0; r < 4; r++) {
      float s_ = rsum[r];
#pragma unroll
      for (int off = 1; off < 16; off <<= 1) s_ += __shfl_xor(s_, off);
      lrow[r] = lrow[r] * alpha[r] + s_;
      mrow[r] = mnew[r];
#pragma unroll
      for (int nt = 0; nt < 4; nt++) Oacc[nt][r] *= alpha[r];
    }

    // O += P @ V  (P from wave-private LDS in A-layout, V^T as B operand)
    half8 ap0 = *(const half8*)&Ps[wave * 1152 + l15 * 72 + 8 * l4];
    half8 ap1 = *(const half8*)&Ps[wave * 1152 + l15 * 72 + 32 + 8 * l4];
#pragma unroll
    for (int nt = 0; nt < 4; nt++) {
      half8 bv0 = *(const half8*)&Vt[(nt * 16 + l15) * 72 + 8 * l4];
      half8 bv1 = *(const half8*)&Vt[(nt * 16 + l15) * 72 + 32 + 8 * l4];
      Oacc[nt] = __builtin_amdgcn_mfma_f32_16x16x32_f16(ap0, bv0, Oacc[nt], 0, 0, 0);
      Oacc[nt] = __builtin_amdgcn_mfma_f32_16x16x32_f16(ap1, bv1, Oacc[nt], 0, 0, 0);
    }
    __syncthreads();
  }

  // finalize + merged write: out[b][s][h*64 + hd]
#pragma unroll
  for (int nt = 0; nt < 4; nt++) {
#pragma unroll
    for (int r = 0; r < 4; r++) {
      const int srow = q0 + wave * 16 + l4 * 4 + r;
      O[((size_t)b * Sn + srow) * Dn + h * HDn + nt * 16 + l15] = Oacc[nt][r] / lrow[r];
    }
  }
}

// ---------------------------------------------------------------------------
// Residual add + LayerNorm over D=768, one block per row (256 thr x 3 elems).
// Emits fp32 (residual chain) and fp16 (next GEMM input).
// ---------------------------------------------------------------------------
__global__ __launch_bounds__(256) void add_ln(
    const float* __restrict__ Xi, const float* __restrict__ Hr,
    const float* __restrict__ g, const float* __restrict__ bt,
    float* __restrict__ Yf, f16* __restrict__ Yh) {
  const int row = blockIdx.x;
  const int tid = threadIdx.x;
  const size_t base = (size_t)row * Dn;
  float v0 = Xi[base + tid] + Hr[base + tid];
  float v1 = Xi[base + tid + 256] + Hr[base + tid + 256];
  float v2 = Xi[base + tid + 512] + Hr[base + tid + 512];

  __shared__ float red[8];
  float s = v0 + v1 + v2;
  for (int off = 32; off; off >>= 1) s += __shfl_down(s, off);
  const int wv = tid >> 6, ln = tid & 63;
  if (ln == 0) red[wv] = s;
  __syncthreads();
  if (tid == 0) red[4] = (red[0] + red[1] + red[2] + red[3]) * (1.f / Dn);
  __syncthreads();
  const float mu = red[4];
  const float d0 = v0 - mu, d1 = v1 - mu, d2 = v2 - mu;
  float vs = d0 * d0 + d1 * d1 + d2 * d2;
  for (int off = 32; off; off >>= 1) vs += __shfl_down(vs, off);
  if (ln == 0) red[wv] = vs;
  __syncthreads();
  if (tid == 0) red[5] = rsqrtf((red[0] + red[1] + red[2] + red[3]) * (1.f / Dn) + 1e-5f);
  __syncthreads();
  const float rs = red[5];
  float y0 = d0 * rs * g[tid] + bt[tid];
  float y1 = d1 * rs * g[tid + 256] + bt[tid + 256];
  float y2 = d2 * rs * g[tid + 512] + bt[tid + 512];
  Yf[base + tid] = y0;        Yh[base + tid] = (f16)y0;
  Yf[base + tid + 256] = y1;  Yh[base + tid + 256] = (f16)y1;
  Yf[base + tid + 512] = y2;  Yh[base + tid + 512] = (f16)y2;
}

// ---------------------------------------------------------------------------
extern "C" void kernel_launch(void* const* d_in, const int* in_sizes, int n_in,
                              void* d_out, int out_size, void* d_ws, size_t ws_size,
                              hipStream_t stream) {
  const int* ids  = (const int*)d_in[0];
  const float* emb = (const float*)d_in[1];
  const float* pe  = (const float*)d_in[2];
  const float* Wq  = (const float*)d_in[3];
  const float* bq  = (const float*)d_in[4];
  const float* Wk  = (const float*)d_in[5];
  const float* bk  = (const float*)d_in[6];
  const float* Wv  = (const float*)d_in[7];
  const float* bv  = (const float*)d_in[8];
  const float* W1  = (const float*)d_in[9];
  const float* b1  = (const float*)d_in[10];
  const float* W2  = (const float*)d_in[11];
  const float* b2  = (const float*)d_in[12];
  const float* g1  = (const float*)d_in[13];
  const float* be1 = (const float*)d_in[14];
  const float* g2  = (const float*)d_in[15];
  const float* be2 = (const float*)d_in[16];
  float* out = (float*)d_out;

  // workspace layout (~292 MB)
  char* w = (char*)d_ws;
  auto alloc = [&](size_t bytes) {
    char* p = w;
    w += (bytes + 255) & ~(size_t)255;
    return p;
  };
  f16* Wqkv  = (f16*)alloc((size_t)Ln * 3 * Dn * Dn * 2);
  float* bqkv = (float*)alloc((size_t)Ln * 3 * Dn * 4);
  f16* W1h   = (f16*)alloc((size_t)Ln * DFn * Dn * 2);
  f16* W2h   = (f16*)alloc((size_t)Ln * Dn * DFn * 2);
  float* Xf  = (float*)alloc((size_t)BS * Dn * 4);
  f16* Xh    = (f16*)alloc((size_t)BS * Dn * 2);
  f16* Qh    = (f16*)alloc((size_t)BS * Dn * 2);
  f16* Kh    = (f16*)alloc((size_t)BS * Dn * 2);
  f16* Vh    = (f16*)alloc((size_t)BS * Dn * 2);
  float* Of  = (float*)alloc((size_t)BS * Dn * 4);
  float* Y1f = (float*)alloc((size_t)BS * Dn * 4);
  f16* Y1h   = (f16*)alloc((size_t)BS * Dn * 2);
  f16* F1h   = (f16*)alloc((size_t)BS * DFn * 2);
  float* H2f = (float*)alloc((size_t)BS * Dn * 4);

  // weight conversion (every call; harness re-poisons ws)
  {
    const int gw = (Ln * 3 * Dn * Dn + 255) / 256;  // 41472 blocks
    pack_qkv<<<gw, 256, 0, stream>>>(Wq, Wk, Wv, bq, bk, bv, Wqkv, bqkv);
    const long n1 = (long)Ln * DFn * Dn;
    const int gc = (int)(n1 / 4 / 256);             // 13824
    f32_to_f16_k<<<gc, 256, 0, stream>>>(W1, W1h, n1);
    f32_to_f16_k<<<gc, 256, 0, stream>>>(W2, W2h, n1);
  }

  embed_k<<<BS, 256, 0, stream>>>(ids, emb, pe, Xf, Xh);

  for (int l = 0; l < Ln; ++l) {
    // QKV: (8192 x 2304) = Xh @ Wqkv^T, split-written to Qh/Kh/Vh
    gemm_bt<3><<<dim3(BS / 128, (3 * Dn) / 128), 256, 0, stream>>>(
        Xh, Wqkv + (size_t)l * 3 * Dn * Dn, bqkv + l * 3 * Dn,
        nullptr, Qh, Kh, Vh, BS, 3 * Dn, Dn);

    attn_k<<<dim3(Bn * Hn, Sn / 64), 256, 0, stream>>>(Qh, Kh, Vh, Of);

    add_ln<<<BS, 256, 0, stream>>>(Xf, Of, g1 + l * Dn, be1 + l * Dn, Y1f, Y1h);

    // FFN1: relu(Y1 @ W1^T + b1) -> fp16
    gemm_bt<1><<<dim3(BS / 128, DFn / 128), 256, 0, stream>>>(
        Y1h, W1h + (size_t)l * DFn * Dn, b1 + l * DFn,
        nullptr, F1h, nullptr, nullptr, BS, DFn, Dn);

    // FFN2: F1 @ W2^T + b2 -> fp32
    gemm_bt<2><<<dim3(BS / 128, Dn / 128), 256, 0, stream>>>(
        F1h, W2h + (size_t)l * Dn * DFn, b2 + l * Dn,
        H2f, nullptr, nullptr, nullptr, BS, Dn, DFn);

    float* dstF = (l == Ln - 1) ? out : Xf;
    add_ln<<<BS, 256, 0, stream>>>(Y1f, H2f, g2 + l * Dn, be2 + l * Dn, dstF, Xh);
  }
}

// Round 4
// 2338.903 us; speedup vs baseline: 1.0494x; 1.0494x over previous
//
#include <hip/hip_runtime.h>

// ---------------------------------------------------------------------------
// 6-layer Transformer encoder, MI355X gfx950.
// fp16 MFMA (16x16x32_f16) GEMMs + flash attention, fp32 residual/LN chain.
// R4: (1) GEMM staging via __builtin_amdgcn_global_load_lds width=16
//     (m97 structure: unpadded 128x32 LDS tiles, 2-barrier K-loop).
//     (2) attn V-transpose staging: 8 scalar col-gathers -> one aligned
//     ds_write_b128 (was 16 scalar 8-way-conflict writes: 1.65e7 conflict cyc).
// ---------------------------------------------------------------------------

typedef _Float16 f16;
typedef _Float16 half8 __attribute__((ext_vector_type(8)));
typedef float f32x4 __attribute__((ext_vector_type(4)));

constexpr int Bn = 8, Sn = 1024, Dn = 768, Hn = 12, HDn = 64, DFn = 3072, Ln = 6;
constexpr int BS = Bn * Sn;  // 8192 rows

__device__ __forceinline__ void glds16(const f16* g, f16* l) {
  // async global->LDS DMA, 16 B/lane; LDS dest = wave-uniform base + lane*16
  __builtin_amdgcn_global_load_lds(
      (const __attribute__((address_space(1))) unsigned int*)g,
      (__attribute__((address_space(3))) unsigned int*)l, 16, 0, 0);
}

// ---------------------------------------------------------------------------
// Weight prep: pack [Wq;Wk;Wv] per layer into (2304 x 768) fp16 + packed bias
// ---------------------------------------------------------------------------
__global__ __launch_bounds__(256) void pack_qkv(
    const float* __restrict__ Wq, const float* __restrict__ Wk, const float* __restrict__ Wv,
    const float* __restrict__ bq, const float* __restrict__ bk, const float* __restrict__ bv,
    f16* __restrict__ Wo, float* __restrict__ bo) {
  const long per = (long)Dn * Dn;  // 589824
  long i = (long)blockIdx.x * 256 + threadIdx.x;
  const long totalW = (long)Ln * 3 * per;
  if (i < totalW) {
    int l = (int)(i / (3 * per));
    long rem = i - (long)l * 3 * per;
    int which = (int)(rem / per);
    long e = rem - (long)which * per;
    const float* s = (which == 0) ? Wq : ((which == 1) ? Wk : Wv);
    Wo[i] = (f16)(s[(long)l * per + e]);
  }
  if (i < (long)Ln * 3 * Dn) {  // 13824 bias elems
    int l = (int)(i / (3 * Dn));
    int rem = (int)(i % (3 * Dn));
    int which = rem / Dn, c = rem % Dn;
    const float* s = (which == 0) ? bq : ((which == 1) ? bk : bv);
    bo[i] = s[l * Dn + c];
  }
}

__global__ __launch_bounds__(256) void f32_to_f16_k(
    const float* __restrict__ src, f16* __restrict__ dst, long n) {
  long i = ((long)blockIdx.x * 256 + threadIdx.x) * 4;
  if (i < n) {
    float4 v = *(const float4*)&src[i];
    dst[i + 0] = (f16)v.x;
    dst[i + 1] = (f16)v.y;
    dst[i + 2] = (f16)v.z;
    dst[i + 3] = (f16)v.w;
  }
}

// ---------------------------------------------------------------------------
// Embedding gather + positional encoding -> fp32 X and fp16 Xh
// ---------------------------------------------------------------------------
__global__ __launch_bounds__(256) void embed_k(
    const int* __restrict__ ids, const float* __restrict__ emb, const float* __restrict__ pe,
    float* __restrict__ Xf, f16* __restrict__ Xh) {
  const int row = blockIdx.x;           // 0..8191
  const int s = row & (Sn - 1);
  const int id = ids[row];
  const size_t eb = (size_t)id * Dn, pb = (size_t)s * Dn, ob = (size_t)row * Dn;
  for (int c = threadIdx.x; c < Dn; c += 256) {
    float v = emb[eb + c] + pe[pb + c];
    Xf[ob + c] = v;
    Xh[ob + c] = (f16)v;
  }
}

// ---------------------------------------------------------------------------
// bt-GEMM: C(M,N) = A(MxK) @ B(NxK)^T + bias, 128x128x32 tile, 4 waves.
// Staging: global_load_lds width=16, unpadded LDS (stride 32 f16) — lane i of
// each DMA lands at base+i*16B, so the layout must be exactly linear (m104).
// MODE 1: relu + fp16 out.  MODE 2: fp32 out.  MODE 3: fp16 QKV split.
// ---------------------------------------------------------------------------
template <int MODE>
__global__ __launch_bounds__(256) void gemm_bt(
    const f16* __restrict__ A, const f16* __restrict__ Bw, const float* __restrict__ bias,
    float* __restrict__ outF, f16* __restrict__ o0, f16* __restrict__ o1, f16* __restrict__ o2,
    int M, int N, int K) {
  const int m0 = blockIdx.x * 128;
  const int n0 = blockIdx.y * 128;
  const int tid = threadIdx.x;
  const int lane = tid & 63, wave = tid >> 6;
  const int wm = wave & 1, wn = wave >> 1;
  const int l15 = lane & 15, l4 = lane >> 4;

  __shared__ __align__(16) f16 As[128 * 32];  // unpadded: required by glds
  __shared__ __align__(16) f16 Bs[128 * 32];

  const f32x4 z4 = {0.f, 0.f, 0.f, 0.f};
  f32x4 acc[4][4];
#pragma unroll
  for (int i = 0; i < 4; i++)
#pragma unroll
    for (int j = 0; j < 4; j++) acc[i][j] = z4;

  // staging geometry: each wave DMAs rows [wave*32, wave*32+32) in 2 instrs;
  // lane L covers row base+L/4, col (L&3)*8  (16 B = 8 f16 per lane)
  const int sRow = wave * 32 + (lane >> 2);
  const int sCol = (lane & 3) * 8;
  const f16* gA = A + (size_t)(m0 + sRow) * K + sCol;
  const f16* gB = Bw + (size_t)(n0 + sRow) * K + sCol;
  f16* lA0 = &As[(wave * 32) * 32];
  f16* lA1 = &As[(wave * 32 + 16) * 32];
  f16* lB0 = &Bs[(wave * 32) * 32];
  f16* lB1 = &Bs[(wave * 32 + 16) * 32];
  const size_t rowStep = (size_t)16 * K;

  const int kr = 8 * l4;
  for (int k0 = 0; k0 < K; k0 += 32) {
    glds16(gA + k0, lA0);
    glds16(gA + k0 + rowStep, lA1);
    glds16(gB + k0, lB0);
    glds16(gB + k0 + rowStep, lB1);
    __syncthreads();  // drains vmcnt -> DMA visible to all waves
    half8 af[4], bfr[4];
#pragma unroll
    for (int i = 0; i < 4; i++) af[i] = *(const half8*)&As[(wm * 64 + i * 16 + l15) * 32 + kr];
#pragma unroll
    for (int j = 0; j < 4; j++) bfr[j] = *(const half8*)&Bs[(wn * 64 + j * 16 + l15) * 32 + kr];
#pragma unroll
    for (int i = 0; i < 4; i++)
#pragma unroll
      for (int j = 0; j < 4; j++)
        acc[i][j] = __builtin_amdgcn_mfma_f32_16x16x32_f16(af[i], bfr[j], acc[i][j], 0, 0, 0);
    __syncthreads();  // all reads done before next iteration's DMA overwrites
  }

  const int colb = n0 + wn * 64;
  const int rowb = m0 + wm * 64;
#pragma unroll
  for (int j = 0; j < 4; j++) {
    const int col = colb + j * 16 + l15;
    const float bb = bias[col];
#pragma unroll
    for (int i = 0; i < 4; i++) {
      const int rb = rowb + i * 16 + l4 * 4;
#pragma unroll
      for (int r = 0; r < 4; r++) {
        float v = acc[i][j][r] + bb;
        const int row = rb + r;
        if (MODE == 1) v = fmaxf(v, 0.f);
        if (MODE == 2) {
          outF[(size_t)row * N + col] = v;
        } else if (MODE == 3) {
          const int sel = col / 768;          // block-uniform (768 % 128 == 0)
          const int cl = col - sel * 768;
          f16* op = (sel == 0) ? o0 : ((sel == 1) ? o1 : o2);
          op[(size_t)row * 768 + cl] = (f16)v;
        } else {
          o0[(size_t)row * N + col] = (f16)v;
        }
      }
    }
  }
}

// ---------------------------------------------------------------------------
// Flash attention: one block = (b,h) x 64 q-rows; 4 waves x 16 rows each.
// K/V tiles of 64 staged in LDS (V transposed via register gather + b128
// write). Online softmax. Output in merged (B,S,D) layout.
// ---------------------------------------------------------------------------
__global__ __launch_bounds__(256) void attn_k(
    const f16* __restrict__ Qg, const f16* __restrict__ Kg, const f16* __restrict__ Vg,
    float* __restrict__ O) {
  const int bh = blockIdx.x;            // 0..95
  const int q0 = blockIdx.y * 64;
  const int b = bh / Hn, h = bh - b * Hn;
  const size_t base = (size_t)b * (Sn * Dn) + (size_t)h * (Sn * HDn);
  const f16* Qh = Qg + base;
  const f16* Kh = Kg + base;
  const f16* Vh = Vg + base;

  const int tid = threadIdx.x, lane = tid & 63, wave = tid >> 6;
  const int l15 = lane & 15, l4 = lane >> 4;

  __shared__ __align__(16) f16 Ks[64 * 72];        // (kpos, hd), padded
  __shared__ __align__(16) f16 Vt[64 * 72];        // (hd, kpos), padded
  __shared__ __align__(16) f16 Ps[4 * 16 * 72];    // per-wave P tile (q, kpos)

  const half8 aq0 = *(const half8*)&Qh[(size_t)(q0 + wave * 16 + l15) * HDn + 8 * l4];
  const half8 aq1 = *(const half8*)&Qh[(size_t)(q0 + wave * 16 + l15) * HDn + 32 + 8 * l4];

  const f32x4 z4 = {0.f, 0.f, 0.f, 0.f};
  f32x4 Oacc[4];
#pragma unroll
  for (int nt = 0; nt < 4; nt++) Oacc[nt] = z4;
  float mrow[4], lrow[4];
#pragma unroll
  for (int r = 0; r < 4; r++) { mrow[r] = -1e30f; lrow[r] = 0.f; }

  for (int kt = 0; kt < Sn / 64; ++kt) {
    // stage K tile: 64x64, 512 chunks of 8 f16
#pragma unroll
    for (int cc = 0; cc < 2; cc++) {
      const int c = tid + cc * 256;
      const int row = c >> 3, col = (c & 7) * 8;
      *(int4*)&Ks[row * 72 + col] = *(const int4*)&Kh[(size_t)(kt * 64 + row) * HDn + col];
    }
    // stage V transposed: gather 8 kpos (coalesced 128B col segments) then one
    // aligned b128 LDS write — was 16 scalar 8-way-conflicted writes
#pragma unroll
    for (int ee = 0; ee < 2; ee++) {
      const int e = tid + ee * 256;               // 0..511
      const int hd = e & 63, kpo = e >> 6;        // kpo: group of 8 kpos
      f16 tmp[8];
#pragma unroll
      for (int j = 0; j < 8; j++)
        tmp[j] = Vh[(size_t)(kt * 64 + kpo * 8 + j) * HDn + hd];
      *(int4*)&Vt[hd * 72 + kpo * 8] = *(const int4*)tmp;
    }
    __syncthreads();

    // scores: S(16x64) = Q(16x64) @ K_tile^T, scaled by 1/sqrt(64)
    f32x4 sc[4];
#pragma unroll
    for (int nt = 0; nt < 4; nt++) {
      f32x4 z = z4;
      half8 bk0 = *(const half8*)&Ks[(nt * 16 + l15) * 72 + 8 * l4];
      half8 bk1 = *(const half8*)&Ks[(nt * 16 + l15) * 72 + 32 + 8 * l4];
      z = __builtin_amdgcn_mfma_f32_16x16x32_f16(aq0, bk0, z, 0, 0, 0);
      z = __builtin_amdgcn_mfma_f32_16x16x32_f16(aq1, bk1, z, 0, 0, 0);
      sc[nt] = z * 0.125f;
    }

    // online softmax: rows r -> C-layout row = 4*l4 + r
    float mnew[4], alpha[4];
#pragma unroll
    for (int r = 0; r < 4; r++) {
      float mx = fmaxf(fmaxf(sc[0][r], sc[1][r]), fmaxf(sc[2][r], sc[3][r]));
#pragma unroll
      for (int off = 1; off < 16; off <<= 1) mx = fmaxf(mx, __shfl_xor(mx, off));
      mnew[r] = fmaxf(mrow[r], mx);
      alpha[r] = __expf(mrow[r] - mnew[r]);
    }
    float rsum[4] = {0.f, 0.f, 0.f, 0.f};
#pragma unroll
    for (int nt = 0; nt < 4; nt++) {
#pragma unroll
      for (int r = 0; r < 4; r++) {
        float p = __expf(sc[nt][r] - mnew[r]);
        rsum[r] += p;
        Ps[wave * 1152 + (l4 * 4 + r) * 72 + nt * 16 + l15] = (f16)p;
      }
    }
#pragma unroll
    for (int r = 0; r < 4; r++) {
      float s_ = rsum[r];
#pragma unroll
      for (int off = 1; off < 16; off <<= 1) s_ += __shfl_xor(s_, off);
      lrow[r] = lrow[r] * alpha[r] + s_;
      mrow[r] = mnew[r];
#pragma unroll
      for (int nt = 0; nt < 4; nt++) Oacc[nt][r] *= alpha[r];
    }

    // O += P @ V  (P from wave-private LDS in A-layout, V^T as B operand)
    half8 ap0 = *(const half8*)&Ps[wave * 1152 + l15 * 72 + 8 * l4];
    half8 ap1 = *(const half8*)&Ps[wave * 1152 + l15 * 72 + 32 + 8 * l4];
#pragma unroll
    for (int nt = 0; nt < 4; nt++) {
      half8 bv0 = *(const half8*)&Vt[(nt * 16 + l15) * 72 + 8 * l4];
      half8 bv1 = *(const half8*)&Vt[(nt * 16 + l15) * 72 + 32 + 8 * l4];
      Oacc[nt] = __builtin_amdgcn_mfma_f32_16x16x32_f16(ap0, bv0, Oacc[nt], 0, 0, 0);
      Oacc[nt] = __builtin_amdgcn_mfma_f32_16x16x32_f16(ap1, bv1, Oacc[nt], 0, 0, 0);
    }
    __syncthreads();
  }

  // finalize + merged write: out[b][s][h*64 + hd]
#pragma unroll
  for (int nt = 0; nt < 4; nt++) {
#pragma unroll
    for (int r = 0; r < 4; r++) {
      const int srow = q0 + wave * 16 + l4 * 4 + r;
      O[((size_t)b * Sn + srow) * Dn + h * HDn + nt * 16 + l15] = Oacc[nt][r] / lrow[r];
    }
  }
}

// ---------------------------------------------------------------------------
// Residual add + LayerNorm over D=768, one block per row (256 thr x 3 elems).
// Emits fp32 (residual chain) and fp16 (next GEMM input).
// ---------------------------------------------------------------------------
__global__ __launch_bounds__(256) void add_ln(
    const float* __restrict__ Xi, const float* __restrict__ Hr,
    const float* __restrict__ g, const float* __restrict__ bt,
    float* __restrict__ Yf, f16* __restrict__ Yh) {
  const int row = blockIdx.x;
  const int tid = threadIdx.x;
  const size_t base = (size_t)row * Dn;
  float v0 = Xi[base + tid] + Hr[base + tid];
  float v1 = Xi[base + tid + 256] + Hr[base + tid + 256];
  float v2 = Xi[base + tid + 512] + Hr[base + tid + 512];

  __shared__ float red[8];
  float s = v0 + v1 + v2;
  for (int off = 32; off; off >>= 1) s += __shfl_down(s, off);
  const int wv = tid >> 6, ln = tid & 63;
  if (ln == 0) red[wv] = s;
  __syncthreads();
  if (tid == 0) red[4] = (red[0] + red[1] + red[2] + red[3]) * (1.f / Dn);
  __syncthreads();
  const float mu = red[4];
  const float d0 = v0 - mu, d1 = v1 - mu, d2 = v2 - mu;
  float vs = d0 * d0 + d1 * d1 + d2 * d2;
  for (int off = 32; off; off >>= 1) vs += __shfl_down(vs, off);
  if (ln == 0) red[wv] = vs;
  __syncthreads();
  if (tid == 0) red[5] = rsqrtf((red[0] + red[1] + red[2] + red[3]) * (1.f / Dn) + 1e-5f);
  __syncthreads();
  const float rs = red[5];
  float y0 = d0 * rs * g[tid] + bt[tid];
  float y1 = d1 * rs * g[tid + 256] + bt[tid + 256];
  float y2 = d2 * rs * g[tid + 512] + bt[tid + 512];
  Yf[base + tid] = y0;        Yh[base + tid] = (f16)y0;
  Yf[base + tid + 256] = y1;  Yh[base + tid + 256] = (f16)y1;
  Yf[base + tid + 512] = y2;  Yh[base + tid + 512] = (f16)y2;
}

// ---------------------------------------------------------------------------
extern "C" void kernel_launch(void* const* d_in, const int* in_sizes, int n_in,
                              void* d_out, int out_size, void* d_ws, size_t ws_size,
                              hipStream_t stream) {
  const int* ids  = (const int*)d_in[0];
  const float* emb = (const float*)d_in[1];
  const float* pe  = (const float*)d_in[2];
  const float* Wq  = (const float*)d_in[3];
  const float* bq  = (const float*)d_in[4];
  const float* Wk  = (const float*)d_in[5];
  const float* bk  = (const float*)d_in[6];
  const float* Wv  = (const float*)d_in[7];
  const float* bv  = (const float*)d_in[8];
  const float* W1  = (const float*)d_in[9];
  const float* b1  = (const float*)d_in[10];
  const float* W2  = (const float*)d_in[11];
  const float* b2  = (const float*)d_in[12];
  const float* g1  = (const float*)d_in[13];
  const float* be1 = (const float*)d_in[14];
  const float* g2  = (const float*)d_in[15];
  const float* be2 = (const float*)d_in[16];
  float* out = (float*)d_out;

  // workspace layout (~292 MB)
  char* w = (char*)d_ws;
  auto alloc = [&](size_t bytes) {
    char* p = w;
    w += (bytes + 255) & ~(size_t)255;
    return p;
  };
  f16* Wqkv  = (f16*)alloc((size_t)Ln * 3 * Dn * Dn * 2);
  float* bqkv = (float*)alloc((size_t)Ln * 3 * Dn * 4);
  f16* W1h   = (f16*)alloc((size_t)Ln * DFn * Dn * 2);
  f16* W2h   = (f16*)alloc((size_t)Ln * Dn * DFn * 2);
  float* Xf  = (float*)alloc((size_t)BS * Dn * 4);
  f16* Xh    = (f16*)alloc((size_t)BS * Dn * 2);
  f16* Qh    = (f16*)alloc((size_t)BS * Dn * 2);
  f16* Kh    = (f16*)alloc((size_t)BS * Dn * 2);
  f16* Vh    = (f16*)alloc((size_t)BS * Dn * 2);
  float* Of  = (float*)alloc((size_t)BS * Dn * 4);
  float* Y1f = (float*)alloc((size_t)BS * Dn * 4);
  f16* Y1h   = (f16*)alloc((size_t)BS * Dn * 2);
  f16* F1h   = (f16*)alloc((size_t)BS * DFn * 2);
  float* H2f = (float*)alloc((size_t)BS * Dn * 4);

  // weight conversion (every call; harness re-poisons ws)
  {
    const int gw = (Ln * 3 * Dn * Dn + 255) / 256;  // 41472 blocks
    pack_qkv<<<gw, 256, 0, stream>>>(Wq, Wk, Wv, bq, bk, bv, Wqkv, bqkv);
    const long n1 = (long)Ln * DFn * Dn;
    const int gc = (int)(n1 / 4 / 256);             // 13824
    f32_to_f16_k<<<gc, 256, 0, stream>>>(W1, W1h, n1);
    f32_to_f16_k<<<gc, 256, 0, stream>>>(W2, W2h, n1);
  }

  embed_k<<<BS, 256, 0, stream>>>(ids, emb, pe, Xf, Xh);

  for (int l = 0; l < Ln; ++l) {
    // QKV: (8192 x 2304) = Xh @ Wqkv^T, split-written to Qh/Kh/Vh
    gemm_bt<3><<<dim3(BS / 128, (3 * Dn) / 128), 256, 0, stream>>>(
        Xh, Wqkv + (size_t)l * 3 * Dn * Dn, bqkv + l * 3 * Dn,
        nullptr, Qh, Kh, Vh, BS, 3 * Dn, Dn);

    attn_k<<<dim3(Bn * Hn, Sn / 64), 256, 0, stream>>>(Qh, Kh, Vh, Of);

    add_ln<<<BS, 256, 0, stream>>>(Xf, Of, g1 + l * Dn, be1 + l * Dn, Y1f, Y1h);

    // FFN1: relu(Y1 @ W1^T + b1) -> fp16
    gemm_bt<1><<<dim3(BS / 128, DFn / 128), 256, 0, stream>>>(
        Y1h, W1h + (size_t)l * DFn * Dn, b1 + l * DFn,
        nullptr, F1h, nullptr, nullptr, BS, DFn, Dn);

    // FFN2: F1 @ W2^T + b2 -> fp32
    gemm_bt<2><<<dim3(BS / 128, Dn / 128), 256, 0, stream>>>(
        F1h, W2h + (size_t)l * Dn * DFn, b2 + l * Dn,
        H2f, nullptr, nullptr, nullptr, BS, Dn, DFn);

    float* dstF = (l == Ln - 1) ? out : Xf;
    add_ln<<<BS, 256, 0, stream>>>(Y1f, H2f, g2 + l * Dn, be2 + l * Dn, dstF, Xh);
  }
}